// Round 1
// baseline (170652.332 us; speedup 1.0000x reference)
//
#include <hip/hip_runtime.h>
#include <cstddef>

#define T_STEPS 4096
#define H_DIM   4096
#define IN_DIM  1024
#define O_DIM   512

__device__ __forceinline__ float sigmoid_f(float v) {
    v = fminf(fmaxf(v, -30.f), 30.f);
    return 1.f / (1.f + __expf(-v));
}
__device__ __forceinline__ float tanh_f(float v) {
    v = fminf(fmaxf(v, -15.f), 15.f);
    float e = __expf(2.f * v);
    return (e - 1.f) / (e + 1.f);
}

// Persistent cooperative kernel: 256 WGs (1/CU) x 512 threads (8 waves).
// Each WG owns 16 rows of W_rec (regs, 128 VGPR/thread), 16 rows of W_in
// (regs, 32 VGPR), 2 rows of W_out (regs, 16 VGPR). One grid barrier per
// timestep via generation-numbered flags + device-scope fences.
__global__ __launch_bounds__(512, 2) void snn_persistent(
    const float* __restrict__ x, const float* __restrict__ Win,
    const float* __restrict__ Wrec, const float* __restrict__ Wout,
    const float* __restrict__ gbias, float* __restrict__ y,
    float* __restrict__ hbuf, unsigned int* __restrict__ flags)
{
    __shared__ __attribute__((aligned(16))) float h_lds[H_DIM];   // 16 KB
    __shared__ __attribute__((aligned(16))) float x_lds[IN_DIM];  // 4 KB
    __shared__ float osc[8][2];

    const int tid = threadIdx.x;
    const int w   = tid >> 6;     // wave 0..7
    const int l   = tid & 63;     // lane
    const int wg  = blockIdx.x;   // 0..255

    const int row0  = wg * 16 + w * 2;  // global hidden rows this wave owns
    const int row1  = row0 + 1;
    const int orow0 = wg * 2;           // output rows this WG owns
    const int orow1 = orow0 + 1;

    // ---- setup: load weights into registers (one-time, coalesced float4) ----
    float4 wr0[16], wr1[16];
    {
        const float4* W4 = (const float4*)Wrec;
        const float4* p0 = W4 + (size_t)row0 * (H_DIM / 4) + l;
        const float4* p1 = W4 + (size_t)row1 * (H_DIM / 4) + l;
        #pragma unroll
        for (int k = 0; k < 16; ++k) { wr0[k] = p0[k * 64]; wr1[k] = p1[k * 64]; }
    }
    float4 wi0[4], wi1[4];
    {
        const float4* W4 = (const float4*)Win;
        const float4* p0 = W4 + (size_t)row0 * (IN_DIM / 4) + l;
        const float4* p1 = W4 + (size_t)row1 * (IN_DIM / 4) + l;
        #pragma unroll
        for (int k = 0; k < 4; ++k) { wi0[k] = p0[k * 64]; wi1[k] = p1[k * 64]; }
    }
    float wo0[8], wo1[8];
    {
        const float* p0 = Wout + (size_t)orow0 * H_DIM + tid;
        const float* p1 = Wout + (size_t)orow1 * H_DIM + tid;
        #pragma unroll
        for (int j = 0; j < 8; ++j) { wo0[j] = p0[j * 512]; wo1[j] = p1[j * 512]; }
    }
    const float gb0  = gbias[row0];
    const float gb1  = gbias[row1];
    const float leak = 0.1f;

    float* buf0 = hbuf;          // h_t for even t (zeroed by host memset for t=0)
    float* buf1 = hbuf + H_DIM;  // h_t for odd t

    #pragma unroll 1
    for (int t = 0; t <= T_STEPS; ++t) {
        float* cur = (t & 1) ? buf1 : buf0;
        float* nxt = (t & 1) ? buf0 : buf1;

        // stage h_t (and x_t) into LDS
        {
            const float4* c4 = (const float4*)cur;
            float4* h4 = (float4*)h_lds;
            h4[tid]       = c4[tid];
            h4[tid + 512] = c4[tid + 512];
        }
        if (t < T_STEPS && tid < 256) {
            ((float4*)x_lds)[tid] = ((const float4*)(x + (size_t)t * IN_DIM))[tid];
        }
        __syncthreads();

        // ---- y[t-1] = W_out · h_t (block-wide split dot over 2 rows) ----
        if (t >= 1) {
            float p0 = 0.f, p1 = 0.f;
            #pragma unroll
            for (int j = 0; j < 8; ++j) {
                float hh = h_lds[tid + j * 512];
                p0 = fmaf(wo0[j], hh, p0);
                p1 = fmaf(wo1[j], hh, p1);
            }
            #pragma unroll
            for (int off = 32; off; off >>= 1) {
                p0 += __shfl_xor(p0, off);
                p1 += __shfl_xor(p1, off);
            }
            if (l == 0) { osc[w][0] = p0; osc[w][1] = p1; }
        }
        if (t == T_STEPS) {  // epilogue: only the final y remains
            __syncthreads();
            if (tid == 0) {
                float s0 = 0.f, s1 = 0.f;
                #pragma unroll
                for (int q = 0; q < 8; ++q) { s0 += osc[q][0]; s1 += osc[q][1]; }
                y[(size_t)(T_STEPS - 1) * O_DIM + orow0] = s0;
                y[(size_t)(T_STEPS - 1) * O_DIM + orow1] = s1;
            }
            break;
        }

        // ---- r = W_rec rows · h_t (registers x LDS) ----
        float4 a0 = make_float4(0.f, 0.f, 0.f, 0.f);
        float4 a1 = make_float4(0.f, 0.f, 0.f, 0.f);
        {
            const float4* h4 = (const float4*)h_lds;
            #pragma unroll
            for (int k = 0; k < 16; ++k) {
                float4 hv = h4[k * 64 + l];
                a0.x = fmaf(wr0[k].x, hv.x, a0.x);
                a0.y = fmaf(wr0[k].y, hv.y, a0.y);
                a0.z = fmaf(wr0[k].z, hv.z, a0.z);
                a0.w = fmaf(wr0[k].w, hv.w, a0.w);
                a1.x = fmaf(wr1[k].x, hv.x, a1.x);
                a1.y = fmaf(wr1[k].y, hv.y, a1.y);
                a1.z = fmaf(wr1[k].z, hv.z, a1.z);
                a1.w = fmaf(wr1[k].w, hv.w, a1.w);
            }
        }
        // ---- i = W_in rows · x_t ----
        float4 b0 = make_float4(0.f, 0.f, 0.f, 0.f);
        float4 b1 = make_float4(0.f, 0.f, 0.f, 0.f);
        {
            const float4* x4 = (const float4*)x_lds;
            #pragma unroll
            for (int k = 0; k < 4; ++k) {
                float4 xv = x4[k * 64 + l];
                b0.x = fmaf(wi0[k].x, xv.x, b0.x);
                b0.y = fmaf(wi0[k].y, xv.y, b0.y);
                b0.z = fmaf(wi0[k].z, xv.z, b0.z);
                b0.w = fmaf(wi0[k].w, xv.w, b0.w);
                b1.x = fmaf(wi1[k].x, xv.x, b1.x);
                b1.y = fmaf(wi1[k].y, xv.y, b1.y);
                b1.z = fmaf(wi1[k].z, xv.z, b1.z);
                b1.w = fmaf(wi1[k].w, xv.w, b1.w);
            }
        }
        float r0 = (a0.x + a0.y) + (a0.z + a0.w);
        float r1 = (a1.x + a1.y) + (a1.z + a1.w);
        float i0 = (b0.x + b0.y) + (b0.z + b0.w);
        float i1 = (b1.x + b1.y) + (b1.z + b1.w);
        #pragma unroll
        for (int off = 32; off; off >>= 1) {
            r0 += __shfl_xor(r0, off);
            r1 += __shfl_xor(r1, off);
            i0 += __shfl_xor(i0, off);
            i1 += __shfl_xor(i1, off);
        }
        if (l == 0) {
            float g0 = sigmoid_f(gb0 + r0);
            float g1 = sigmoid_f(gb1 + r1);
            float z0 = tanh_f(fmaf(g0, r0, i0));
            float z1 = tanh_f(fmaf(g1, r1, i1));
            float h0 = h_lds[row0];
            float h1 = h_lds[row1];
            nxt[row0] = fmaf(leak, z0 - h0, h0);
            nxt[row1] = fmaf(leak, z1 - h1, h1);
        }
        __syncthreads();  // drains each thread's vmcnt: all h stores are in L2

        // ---- grid barrier (generation t+1) ----
        if (tid == 0) {
            if (t >= 1) {
                float s0 = 0.f, s1 = 0.f;
                #pragma unroll
                for (int q = 0; q < 8; ++q) { s0 += osc[q][0]; s1 += osc[q][1]; }
                y[(size_t)(t - 1) * O_DIM + orow0] = s0;
                y[(size_t)(t - 1) * O_DIM + orow1] = s1;
            }
            __threadfence();  // L2 writeback: h_{t+1} visible device-wide
            __hip_atomic_store(&flags[wg], (unsigned)(t + 1),
                               __ATOMIC_RELAXED, __HIP_MEMORY_SCOPE_AGENT);
        }
        if (tid < 256) {
            const unsigned tgt = (unsigned)(t + 1);
            while (__hip_atomic_load(&flags[tid], __ATOMIC_RELAXED,
                                     __HIP_MEMORY_SCOPE_AGENT) < tgt) {}
        }
        __threadfence();  // invalidate stale L1/L2 before reading new h
        __syncthreads();
    }
}

extern "C" void kernel_launch(void* const* d_in, const int* in_sizes, int n_in,
                              void* d_out, int out_size, void* d_ws, size_t ws_size,
                              hipStream_t stream) {
    const float* x     = (const float*)d_in[0];
    const float* Win   = (const float*)d_in[1];
    const float* Wrec  = (const float*)d_in[2];
    const float* Wout  = (const float*)d_in[3];
    const float* gbias = (const float*)d_in[4];
    float* y = (float*)d_out;

    float* hbuf = (float*)d_ws;                                    // 2 x 4096 fp32
    unsigned int* flags = (unsigned int*)((char*)d_ws + 2 * H_DIM * sizeof(float));

    // ws is re-poisoned to 0xAA before every replay: zero h0 + flags each call.
    hipMemsetAsync(d_ws, 0, 2 * H_DIM * sizeof(float) + 256 * sizeof(unsigned int),
                   stream);

    void* args[] = { (void*)&x, (void*)&Win, (void*)&Wrec, (void*)&Wout,
                     (void*)&gbias, (void*)&y, (void*)&hbuf, (void*)&flags };
    hipLaunchCooperativeKernel((const void*)snn_persistent, dim3(256), dim3(512),
                               args, 0, stream);
}

// Round 2
// 163623.499 us; speedup vs baseline: 1.0430x; 1.0430x over previous
//
#include <hip/hip_runtime.h>
#include <cstddef>

#define T_STEPS 4096
#define H_DIM   4096
#define IN_DIM  1024
#define O_DIM   512

__device__ __forceinline__ float sigmoid_f(float v) {
    v = fminf(fmaxf(v, -30.f), 30.f);
    return 1.f / (1.f + __expf(-v));
}
__device__ __forceinline__ float tanh_f(float v) {
    v = fminf(fmaxf(v, -15.f), 15.f);
    float e = __expf(2.f * v);
    return (e - 1.f) / (e + 1.f);
}

// Persistent cooperative kernel: 256 WGs (1/CU) x 512 threads (8 waves).
// Each WG owns 16 rows of W_rec (regs, 128 VGPR/thread), 16 rows of W_in
// (regs, 32 VGPR), 2 rows of W_out (regs, 16 VGPR). One grid barrier per
// timestep via generation-numbered flags + device-scope fences.
//
// amdgpu_waves_per_eu(2,2): R1 showed the allocator capping at 128 VGPRs
// (chasing 4 waves/EU that a 256-block grid can never use) and spilling
// the weight arrays to scratch (FETCH_SIZE 636 MB, 42 us/step). Exact
// range (2,2) gives the allocator the full 256-VGPR budget.
__global__
__attribute__((amdgpu_flat_work_group_size(512, 512), amdgpu_waves_per_eu(2, 2)))
void snn_persistent(
    const float* __restrict__ x, const float* __restrict__ Win,
    const float* __restrict__ Wrec, const float* __restrict__ Wout,
    const float* __restrict__ gbias, float* __restrict__ y,
    float* __restrict__ hbuf, unsigned int* __restrict__ flags)
{
    __shared__ __attribute__((aligned(16))) float h_lds[H_DIM];   // 16 KB
    __shared__ __attribute__((aligned(16))) float x_lds[IN_DIM];  // 4 KB
    __shared__ float osc[8][2];

    const int tid = threadIdx.x;
    const int w   = tid >> 6;     // wave 0..7
    const int l   = tid & 63;     // lane
    const int wg  = blockIdx.x;   // 0..255

    const int row0  = wg * 16 + w * 2;  // global hidden rows this wave owns
    const int row1  = row0 + 1;
    const int orow0 = wg * 2;           // output rows this WG owns
    const int orow1 = orow0 + 1;

    // ---- setup: load weights into registers (one-time, coalesced float4) ----
    float4 wr0[16], wr1[16];
    {
        const float4* W4 = (const float4*)Wrec;
        const float4* p0 = W4 + (size_t)row0 * (H_DIM / 4) + l;
        const float4* p1 = W4 + (size_t)row1 * (H_DIM / 4) + l;
        #pragma unroll
        for (int k = 0; k < 16; ++k) { wr0[k] = p0[k * 64]; wr1[k] = p1[k * 64]; }
    }
    float4 wi0[4], wi1[4];
    {
        const float4* W4 = (const float4*)Win;
        const float4* p0 = W4 + (size_t)row0 * (IN_DIM / 4) + l;
        const float4* p1 = W4 + (size_t)row1 * (IN_DIM / 4) + l;
        #pragma unroll
        for (int k = 0; k < 4; ++k) { wi0[k] = p0[k * 64]; wi1[k] = p1[k * 64]; }
    }
    float wo0[8], wo1[8];
    {
        const float* p0 = Wout + (size_t)orow0 * H_DIM + tid;
        const float* p1 = Wout + (size_t)orow1 * H_DIM + tid;
        #pragma unroll
        for (int j = 0; j < 8; ++j) { wo0[j] = p0[j * 512]; wo1[j] = p1[j * 512]; }
    }
    const float gb0  = gbias[row0];
    const float gb1  = gbias[row1];
    const float leak = 0.1f;

    float* buf0 = hbuf;          // h_t for even t (zeroed by host memset for t=0)
    float* buf1 = hbuf + H_DIM;  // h_t for odd t

    #pragma unroll 1
    for (int t = 0; t <= T_STEPS; ++t) {
        float* cur = (t & 1) ? buf1 : buf0;
        float* nxt = (t & 1) ? buf0 : buf1;

        // stage h_t (and x_t) into LDS
        {
            const float4* c4 = (const float4*)cur;
            float4* h4 = (float4*)h_lds;
            h4[tid]       = c4[tid];
            h4[tid + 512] = c4[tid + 512];
        }
        if (t < T_STEPS && tid < 256) {
            ((float4*)x_lds)[tid] = ((const float4*)(x + (size_t)t * IN_DIM))[tid];
        }
        __syncthreads();

        // ---- y[t-1] = W_out · h_t (block-wide split dot over 2 rows) ----
        if (t >= 1) {
            float p0 = 0.f, p1 = 0.f;
            #pragma unroll
            for (int j = 0; j < 8; ++j) {
                float hh = h_lds[tid + j * 512];
                p0 = fmaf(wo0[j], hh, p0);
                p1 = fmaf(wo1[j], hh, p1);
            }
            #pragma unroll
            for (int off = 32; off; off >>= 1) {
                p0 += __shfl_xor(p0, off);
                p1 += __shfl_xor(p1, off);
            }
            if (l == 0) { osc[w][0] = p0; osc[w][1] = p1; }
        }
        if (t == T_STEPS) {  // epilogue: only the final y remains
            __syncthreads();
            if (tid == 0) {
                float s0 = 0.f, s1 = 0.f;
                #pragma unroll
                for (int q = 0; q < 8; ++q) { s0 += osc[q][0]; s1 += osc[q][1]; }
                y[(size_t)(T_STEPS - 1) * O_DIM + orow0] = s0;
                y[(size_t)(T_STEPS - 1) * O_DIM + orow1] = s1;
            }
            break;
        }

        // ---- r = W_rec rows · h_t (registers x LDS) ----
        float4 a0 = make_float4(0.f, 0.f, 0.f, 0.f);
        float4 a1 = make_float4(0.f, 0.f, 0.f, 0.f);
        {
            const float4* h4 = (const float4*)h_lds;
            #pragma unroll
            for (int k = 0; k < 16; ++k) {
                float4 hv = h4[k * 64 + l];
                a0.x = fmaf(wr0[k].x, hv.x, a0.x);
                a0.y = fmaf(wr0[k].y, hv.y, a0.y);
                a0.z = fmaf(wr0[k].z, hv.z, a0.z);
                a0.w = fmaf(wr0[k].w, hv.w, a0.w);
                a1.x = fmaf(wr1[k].x, hv.x, a1.x);
                a1.y = fmaf(wr1[k].y, hv.y, a1.y);
                a1.z = fmaf(wr1[k].z, hv.z, a1.z);
                a1.w = fmaf(wr1[k].w, hv.w, a1.w);
            }
        }
        // ---- i = W_in rows · x_t ----
        float4 b0 = make_float4(0.f, 0.f, 0.f, 0.f);
        float4 b1 = make_float4(0.f, 0.f, 0.f, 0.f);
        {
            const float4* x4 = (const float4*)x_lds;
            #pragma unroll
            for (int k = 0; k < 4; ++k) {
                float4 xv = x4[k * 64 + l];
                b0.x = fmaf(wi0[k].x, xv.x, b0.x);
                b0.y = fmaf(wi0[k].y, xv.y, b0.y);
                b0.z = fmaf(wi0[k].z, xv.z, b0.z);
                b0.w = fmaf(wi0[k].w, xv.w, b0.w);
                b1.x = fmaf(wi1[k].x, xv.x, b1.x);
                b1.y = fmaf(wi1[k].y, xv.y, b1.y);
                b1.z = fmaf(wi1[k].z, xv.z, b1.z);
                b1.w = fmaf(wi1[k].w, xv.w, b1.w);
            }
        }
        float r0 = (a0.x + a0.y) + (a0.z + a0.w);
        float r1 = (a1.x + a1.y) + (a1.z + a1.w);
        float i0 = (b0.x + b0.y) + (b0.z + b0.w);
        float i1 = (b1.x + b1.y) + (b1.z + b1.w);
        #pragma unroll
        for (int off = 32; off; off >>= 1) {
            r0 += __shfl_xor(r0, off);
            r1 += __shfl_xor(r1, off);
            i0 += __shfl_xor(i0, off);
            i1 += __shfl_xor(i1, off);
        }
        if (l == 0) {
            float g0 = sigmoid_f(gb0 + r0);
            float g1 = sigmoid_f(gb1 + r1);
            float z0 = tanh_f(fmaf(g0, r0, i0));
            float z1 = tanh_f(fmaf(g1, r1, i1));
            float h0 = h_lds[row0];
            float h1 = h_lds[row1];
            nxt[row0] = fmaf(leak, z0 - h0, h0);
            nxt[row1] = fmaf(leak, z1 - h1, h1);
        }
        __syncthreads();  // drains each wave's vmcnt: all h stores are in L2

        // ---- grid barrier (generation t+1) ----
        if (tid == 0) {
            if (t >= 1) {
                float s0 = 0.f, s1 = 0.f;
                #pragma unroll
                for (int q = 0; q < 8; ++q) { s0 += osc[q][0]; s1 += osc[q][1]; }
                y[(size_t)(t - 1) * O_DIM + orow0] = s0;
                y[(size_t)(t - 1) * O_DIM + orow1] = s1;
            }
            __threadfence();  // L2 writeback: h_{t+1} visible device-wide
            __hip_atomic_store(&flags[wg], (unsigned)(t + 1),
                               __ATOMIC_RELAXED, __HIP_MEMORY_SCOPE_AGENT);
        }
        if (tid < 256) {
            const unsigned tgt = (unsigned)(t + 1);
            while (__hip_atomic_load(&flags[tid], __ATOMIC_RELAXED,
                                     __HIP_MEMORY_SCOPE_AGENT) < tgt) {}
        }
        __threadfence();  // invalidate stale L1/L2 before reading new h
        __syncthreads();
    }
}

extern "C" void kernel_launch(void* const* d_in, const int* in_sizes, int n_in,
                              void* d_out, int out_size, void* d_ws, size_t ws_size,
                              hipStream_t stream) {
    const float* x     = (const float*)d_in[0];
    const float* Win   = (const float*)d_in[1];
    const float* Wrec  = (const float*)d_in[2];
    const float* Wout  = (const float*)d_in[3];
    const float* gbias = (const float*)d_in[4];
    float* y = (float*)d_out;

    float* hbuf = (float*)d_ws;                                    // 2 x 4096 fp32
    unsigned int* flags = (unsigned int*)((char*)d_ws + 2 * H_DIM * sizeof(float));

    // ws is re-poisoned to 0xAA before every replay: zero h0 + flags each call.
    hipMemsetAsync(d_ws, 0, 2 * H_DIM * sizeof(float) + 256 * sizeof(unsigned int),
                   stream);

    void* args[] = { (void*)&x, (void*)&Win, (void*)&Wrec, (void*)&Wout,
                     (void*)&gbias, (void*)&y, (void*)&hbuf, (void*)&flags };
    hipLaunchCooperativeKernel((const void*)snn_persistent, dim3(256), dim3(512),
                               args, 0, stream);
}